// Round 1
// baseline (375.623 us; speedup 1.0000x reference)
//
#include <hip/hip_runtime.h>

#define HID 128
#define NIN 21
#define EIN 2
#define NCLS 4

__device__ __forceinline__ float sigmoid_(float x) {
    return 1.0f / (1.0f + __expf(-x));
}
__device__ __forceinline__ float tanh_(float x) {
    // tanh(x) = 2*sigmoid(2x) - 1 ; robust at extremes (exp -> inf gives -1/+1)
    return 2.0f / (1.0f + __expf(-2.0f * x)) - 1.0f;
}

__global__ __launch_bounds__(256)
void fused_gnn_kernel(const float* __restrict__ node_feat,  // N*21
                      const float* __restrict__ edge_feat,  // N*2
                      const float* __restrict__ W_ih_n,     // 512*21
                      const float* __restrict__ b_ih_n,     // 512
                      const float* __restrict__ b_hh_n,     // 512
                      const float* __restrict__ W_ih_e,     // 512*2
                      const float* __restrict__ b_ih_e,     // 512
                      const float* __restrict__ b_hh_e,     // 512
                      const float* __restrict__ W_nmpn,     // 21*256
                      const float* __restrict__ b_nmpn,     // 21
                      const float* __restrict__ W_fc,       // 4*128
                      const float* __restrict__ b_fc,       // 4
                      float* __restrict__ out,              // N*4
                      int N)
{
    const int n = blockIdx.x * blockDim.x + threadIdx.x;
    if (n >= N) return;

    // ---- load this node's inputs (per-lane) ----
    float xn[NIN];
#pragma unroll
    for (int k = 0; k < NIN; ++k) xn[k] = node_feat[n * NIN + k];
    const float xe0 = edge_feat[n * EIN + 0];
    const float xe1 = edge_feat[n * EIN + 1];

    // running accumulators
    float acc[NIN];   // pre-activation of xn1 (message-pass output)
#pragma unroll
    for (int k = 0; k < NIN; ++k) acc[k] = b_nmpn[k];
    float lg[NCLS];   // logits
#pragma unroll
    for (int k = 0; k < NCLS; ++k) lg[k] = b_fc[k];

    // ================= iteration 1 =================
    // stream over hidden dim d; h values never materialize as arrays
    for (int d = 0; d < HID; ++d) {
        // node LSTM gates i (row d), g (row 256+d), o (row 384+d)
        const float* wi = &W_ih_n[(0 * HID + d) * NIN];
        const float* wg = &W_ih_n[(2 * HID + d) * NIN];
        const float* wo = &W_ih_n[(3 * HID + d) * NIN];
        float gi = b_ih_n[0 * HID + d] + b_hh_n[0 * HID + d];
        float gg = b_ih_n[2 * HID + d] + b_hh_n[2 * HID + d];
        float go = b_ih_n[3 * HID + d] + b_hh_n[3 * HID + d];
#pragma unroll
        for (int k = 0; k < NIN; ++k) {
            gi = fmaf(xn[k], wi[k], gi);
            gg = fmaf(xn[k], wg[k], gg);
            go = fmaf(xn[k], wo[k], go);
        }
        const float cn = sigmoid_(gi) * tanh_(gg);
        const float hn = sigmoid_(go) * tanh_(cn);

        // edge LSTM gates (2 inputs)
        float ei = b_ih_e[0 * HID + d] + b_hh_e[0 * HID + d]
                 + xe0 * W_ih_e[(0 * HID + d) * EIN + 0]
                 + xe1 * W_ih_e[(0 * HID + d) * EIN + 1];
        float eg = b_ih_e[2 * HID + d] + b_hh_e[2 * HID + d]
                 + xe0 * W_ih_e[(2 * HID + d) * EIN + 0]
                 + xe1 * W_ih_e[(2 * HID + d) * EIN + 1];
        float eo = b_ih_e[3 * HID + d] + b_hh_e[3 * HID + d]
                 + xe0 * W_ih_e[(3 * HID + d) * EIN + 0]
                 + xe1 * W_ih_e[(3 * HID + d) * EIN + 1];
        const float ce = sigmoid_(ei) * tanh_(eg);
        const float he = sigmoid_(eo) * tanh_(ce);

        // message-pass accumulation: cat_n = [mail(=h_e), h_n]
        // xn1_pre[k] += he*W_nmpn[k][d] + hn*W_nmpn[k][128+d]
#pragma unroll
        for (int k = 0; k < NIN; ++k) {
            acc[k] = fmaf(he, W_nmpn[k * 2 * HID + d], acc[k]);
            acc[k] = fmaf(hn, W_nmpn[k * 2 * HID + HID + d], acc[k]);
        }
    }

    // xn1 = sigmoid(acc)  (reuse xn storage)
#pragma unroll
    for (int k = 0; k < NIN; ++k) xn[k] = sigmoid_(acc[k]);

    // ================= iteration 2 (only h_n matters) =================
    for (int d = 0; d < HID; ++d) {
        const float* wi = &W_ih_n[(0 * HID + d) * NIN];
        const float* wg = &W_ih_n[(2 * HID + d) * NIN];
        const float* wo = &W_ih_n[(3 * HID + d) * NIN];
        float gi = b_ih_n[0 * HID + d] + b_hh_n[0 * HID + d];
        float gg = b_ih_n[2 * HID + d] + b_hh_n[2 * HID + d];
        float go = b_ih_n[3 * HID + d] + b_hh_n[3 * HID + d];
#pragma unroll
        for (int k = 0; k < NIN; ++k) {
            gi = fmaf(xn[k], wi[k], gi);
            gg = fmaf(xn[k], wg[k], gg);
            go = fmaf(xn[k], wo[k], go);
        }
        const float cn = sigmoid_(gi) * tanh_(gg);
        const float hn = sigmoid_(go) * tanh_(cn);

        // logits accumulation
#pragma unroll
        for (int k = 0; k < NCLS; ++k) {
            lg[k] = fmaf(hn, W_fc[k * HID + d], lg[k]);
        }
    }

    // ================= log_softmax over 4 classes =================
    float m = fmaxf(fmaxf(lg[0], lg[1]), fmaxf(lg[2], lg[3]));
    float s = 0.0f;
#pragma unroll
    for (int k = 0; k < NCLS; ++k) s += __expf(lg[k] - m);
    const float lse = __logf(s) + m;

    float4 o4;
    o4.x = lg[0] - lse;
    o4.y = lg[1] - lse;
    o4.z = lg[2] - lse;
    o4.w = lg[3] - lse;
    *reinterpret_cast<float4*>(&out[n * NCLS]) = o4;
}

extern "C" void kernel_launch(void* const* d_in, const int* in_sizes, int n_in,
                              void* d_out, int out_size, void* d_ws, size_t ws_size,
                              hipStream_t stream)
{
    // setup_inputs order:
    // 0 node_feat, 1 edge_feat, 2 src, 3 dst, 4 W_ih_n, 5 W_hh_n, 6 b_ih_n,
    // 7 b_hh_n, 8 W_ih_e, 9 W_hh_e, 10 b_ih_e, 11 b_hh_e, 12 W_nmpn,
    // 13 b_nmpn, 14 W_empn, 15 b_empn, 16 W_fc, 17 b_fc
    const float* node_feat = (const float*)d_in[0];
    const float* edge_feat = (const float*)d_in[1];
    const float* W_ih_n    = (const float*)d_in[4];
    const float* b_ih_n    = (const float*)d_in[6];
    const float* b_hh_n    = (const float*)d_in[7];
    const float* W_ih_e    = (const float*)d_in[8];
    const float* b_ih_e    = (const float*)d_in[10];
    const float* b_hh_e    = (const float*)d_in[11];
    const float* W_nmpn    = (const float*)d_in[12];
    const float* b_nmpn    = (const float*)d_in[13];
    const float* W_fc      = (const float*)d_in[16];
    const float* b_fc      = (const float*)d_in[17];
    float* out = (float*)d_out;

    const int N = in_sizes[0] / NIN;

    const int block = 256;
    const int grid = (N + block - 1) / block;
    fused_gnn_kernel<<<grid, block, 0, stream>>>(
        node_feat, edge_feat,
        W_ih_n, b_ih_n, b_hh_n,
        W_ih_e, b_ih_e, b_hh_e,
        W_nmpn, b_nmpn, W_fc, b_fc,
        out, N);
}

// Round 2
// 293.948 us; speedup vs baseline: 1.2779x; 1.2779x over previous
//
#include <hip/hip_runtime.h>

#define HID 128
#define NIN 21
#define EIN 2
#define NCLS 4
#define NPT 2   // nodes per thread

__device__ __forceinline__ float rcp_(float x) {
    return __builtin_amdgcn_rcpf(x);   // raw v_rcp_f32, ~1 ulp — fine at 3.3e-2 threshold
}
__device__ __forceinline__ float sigmoid_(float x) {
    return rcp_(1.0f + __expf(-x));
}
__device__ __forceinline__ float tanh_(float x) {
    // tanh(x) = 2/(1+exp(-2x)) - 1 ; robust at extremes
    return fmaf(2.0f, rcp_(1.0f + __expf(-2.0f * x)), -1.0f);
}

__global__ __launch_bounds__(256, 2)   // allow up to 256 VGPR: kill scratch spills
void fused_gnn_kernel(const float* __restrict__ node_feat,  // N*21
                      const float* __restrict__ edge_feat,  // N*2
                      const float* __restrict__ W_ih_n,     // 512*21
                      const float* __restrict__ b_ih_n,     // 512
                      const float* __restrict__ b_hh_n,     // 512
                      const float* __restrict__ W_ih_e,     // 512*2
                      const float* __restrict__ b_ih_e,     // 512
                      const float* __restrict__ b_hh_e,     // 512
                      const float* __restrict__ W_nmpn,     // 21*256
                      const float* __restrict__ b_nmpn,     // 21
                      const float* __restrict__ W_fc,       // 4*128
                      const float* __restrict__ b_fc,       // 4
                      float* __restrict__ out,              // N*4
                      int N)
{
    const int tid = threadIdx.x;
    const int n0 = blockIdx.x * (256 * NPT) + tid;

    int  nidx[NPT];
    bool live[NPT];
#pragma unroll
    for (int j = 0; j < NPT; ++j) {
        const int n = n0 + j * 256;
        live[j] = (n < N);
        nidx[j] = live[j] ? n : (N - 1);
    }

    // ---- per-node inputs ----
    float xn[NPT][NIN];
    float xe0[NPT], xe1[NPT];
#pragma unroll
    for (int j = 0; j < NPT; ++j) {
#pragma unroll
        for (int k = 0; k < NIN; ++k) xn[j][k] = node_feat[nidx[j] * NIN + k];
        xe0[j] = edge_feat[nidx[j] * EIN + 0];
        xe1[j] = edge_feat[nidx[j] * EIN + 1];
    }

    // running accumulators
    float acc[NPT][NIN];
    float lg[NPT][NCLS];
#pragma unroll
    for (int j = 0; j < NPT; ++j) {
#pragma unroll
        for (int k = 0; k < NIN; ++k) acc[j][k] = b_nmpn[k];
#pragma unroll
        for (int k = 0; k < NCLS; ++k) lg[j][k] = b_fc[k];
    }

    // ================= iteration 1 =================
    for (int d = 0; d < HID; ++d) {
        // uniform (per-wave scalar) weight/bias loads, shared across NPT nodes
        const float bi = b_ih_n[0 * HID + d] + b_hh_n[0 * HID + d];
        const float bg = b_ih_n[2 * HID + d] + b_hh_n[2 * HID + d];
        const float bo = b_ih_n[3 * HID + d] + b_hh_n[3 * HID + d];
        const float* wi = &W_ih_n[(0 * HID + d) * NIN];
        const float* wg = &W_ih_n[(2 * HID + d) * NIN];
        const float* wo = &W_ih_n[(3 * HID + d) * NIN];

        const float ebi = b_ih_e[0 * HID + d] + b_hh_e[0 * HID + d];
        const float ebg = b_ih_e[2 * HID + d] + b_hh_e[2 * HID + d];
        const float ebo = b_ih_e[3 * HID + d] + b_hh_e[3 * HID + d];
        const float ewi0 = W_ih_e[(0 * HID + d) * EIN + 0], ewi1 = W_ih_e[(0 * HID + d) * EIN + 1];
        const float ewg0 = W_ih_e[(2 * HID + d) * EIN + 0], ewg1 = W_ih_e[(2 * HID + d) * EIN + 1];
        const float ewo0 = W_ih_e[(3 * HID + d) * EIN + 0], ewo1 = W_ih_e[(3 * HID + d) * EIN + 1];

#pragma unroll
        for (int j = 0; j < NPT; ++j) {
            float gi = bi, gg = bg, go = bo;
#pragma unroll
            for (int k = 0; k < NIN; ++k) {
                gi = fmaf(xn[j][k], wi[k], gi);
                gg = fmaf(xn[j][k], wg[k], gg);
                go = fmaf(xn[j][k], wo[k], go);
            }
            const float cn = sigmoid_(gi) * tanh_(gg);
            const float hn = sigmoid_(go) * tanh_(cn);

            const float ei = fmaf(xe0[j], ewi0, fmaf(xe1[j], ewi1, ebi));
            const float eg = fmaf(xe0[j], ewg0, fmaf(xe1[j], ewg1, ebg));
            const float eo = fmaf(xe0[j], ewo0, fmaf(xe1[j], ewo1, ebo));
            const float ce = sigmoid_(ei) * tanh_(eg);
            const float he = sigmoid_(eo) * tanh_(ce);

            // cat_n = [mail(=h_e), h_n] ; xn1_pre[k] += he*W[k][d] + hn*W[k][128+d]
#pragma unroll
            for (int k = 0; k < NIN; ++k) {
                acc[j][k] = fmaf(he, W_nmpn[k * 2 * HID + d], acc[j][k]);
                acc[j][k] = fmaf(hn, W_nmpn[k * 2 * HID + HID + d], acc[j][k]);
            }
        }
    }

    // xn1 = sigmoid(acc)
#pragma unroll
    for (int j = 0; j < NPT; ++j)
#pragma unroll
        for (int k = 0; k < NIN; ++k) xn[j][k] = sigmoid_(acc[j][k]);

    // ================= iteration 2 (only h_n matters) =================
    for (int d = 0; d < HID; ++d) {
        const float bi = b_ih_n[0 * HID + d] + b_hh_n[0 * HID + d];
        const float bg = b_ih_n[2 * HID + d] + b_hh_n[2 * HID + d];
        const float bo = b_ih_n[3 * HID + d] + b_hh_n[3 * HID + d];
        const float* wi = &W_ih_n[(0 * HID + d) * NIN];
        const float* wg = &W_ih_n[(2 * HID + d) * NIN];
        const float* wo = &W_ih_n[(3 * HID + d) * NIN];
        const float wf0 = W_fc[0 * HID + d];
        const float wf1 = W_fc[1 * HID + d];
        const float wf2 = W_fc[2 * HID + d];
        const float wf3 = W_fc[3 * HID + d];

#pragma unroll
        for (int j = 0; j < NPT; ++j) {
            float gi = bi, gg = bg, go = bo;
#pragma unroll
            for (int k = 0; k < NIN; ++k) {
                gi = fmaf(xn[j][k], wi[k], gi);
                gg = fmaf(xn[j][k], wg[k], gg);
                go = fmaf(xn[j][k], wo[k], go);
            }
            const float cn = sigmoid_(gi) * tanh_(gg);
            const float hn = sigmoid_(go) * tanh_(cn);

            lg[j][0] = fmaf(hn, wf0, lg[j][0]);
            lg[j][1] = fmaf(hn, wf1, lg[j][1]);
            lg[j][2] = fmaf(hn, wf2, lg[j][2]);
            lg[j][3] = fmaf(hn, wf3, lg[j][3]);
        }
    }

    // ================= log_softmax over 4 classes + store =================
#pragma unroll
    for (int j = 0; j < NPT; ++j) {
        const float m = fmaxf(fmaxf(lg[j][0], lg[j][1]), fmaxf(lg[j][2], lg[j][3]));
        float s = 0.0f;
#pragma unroll
        for (int k = 0; k < NCLS; ++k) s += __expf(lg[j][k] - m);
        const float lse = __logf(s) + m;

        if (live[j]) {
            float4 o4;
            o4.x = lg[j][0] - lse;
            o4.y = lg[j][1] - lse;
            o4.z = lg[j][2] - lse;
            o4.w = lg[j][3] - lse;
            *reinterpret_cast<float4*>(&out[nidx[j] * NCLS]) = o4;
        }
    }
}

extern "C" void kernel_launch(void* const* d_in, const int* in_sizes, int n_in,
                              void* d_out, int out_size, void* d_ws, size_t ws_size,
                              hipStream_t stream)
{
    // setup_inputs order:
    // 0 node_feat, 1 edge_feat, 2 src, 3 dst, 4 W_ih_n, 5 W_hh_n, 6 b_ih_n,
    // 7 b_hh_n, 8 W_ih_e, 9 W_hh_e, 10 b_ih_e, 11 b_hh_e, 12 W_nmpn,
    // 13 b_nmpn, 14 W_empn, 15 b_empn, 16 W_fc, 17 b_fc
    const float* node_feat = (const float*)d_in[0];
    const float* edge_feat = (const float*)d_in[1];
    const float* W_ih_n    = (const float*)d_in[4];
    const float* b_ih_n    = (const float*)d_in[6];
    const float* b_hh_n    = (const float*)d_in[7];
    const float* W_ih_e    = (const float*)d_in[8];
    const float* b_ih_e    = (const float*)d_in[10];
    const float* b_hh_e    = (const float*)d_in[11];
    const float* W_nmpn    = (const float*)d_in[12];
    const float* b_nmpn    = (const float*)d_in[13];
    const float* W_fc      = (const float*)d_in[16];
    const float* b_fc      = (const float*)d_in[17];
    float* out = (float*)d_out;

    const int N = in_sizes[0] / NIN;

    const int block = 256;
    const int grid = (N + block * NPT - 1) / (block * NPT);
    fused_gnn_kernel<<<grid, block, 0, stream>>>(
        node_feat, edge_feat,
        W_ih_n, b_ih_n, b_hh_n,
        W_ih_e, b_ih_e, b_hh_e,
        W_nmpn, b_nmpn, W_fc, b_fc,
        out, N);
}

// Round 3
// 271.588 us; speedup vs baseline: 1.3831x; 1.0823x over previous
//
#include <hip/hip_runtime.h>

#define HID 128
#define NIN 21
#define EIN 2
#define NCLS 4

// LDS row layout (per hidden-dim d), stride 124 floats (496B = 31*16B, 16B-aligned):
//  [0..62]   node-gate weights interleaved as triples: (wi_k, wg_k, wo_k) for k=0..20
//  [63..65]  combined node biases: bi, bg, bo  (b_ih + b_hh)
//  [66..71]  edge weights: ewi0,ewi1, ewg0,ewg1, ewo0,ewo1
//  [72..74]  combined edge biases: ebi, ebg, ebo
//  [75..95]  W_nmpn[k][d]      (he coefficients), k=0..20
//  [96..116] W_nmpn[k][128+d]  (hn coefficients), k=0..20
//  [117..120] W_fc[c][d], c=0..3
#define WSTRIDE 124

__device__ __forceinline__ float rcp_(float x) {
    return __builtin_amdgcn_rcpf(x);
}
__device__ __forceinline__ float sigmoid_(float x) {
    return rcp_(1.0f + __expf(-x));
}
__device__ __forceinline__ float tanh_(float x) {
    return fmaf(2.0f, rcp_(1.0f + __expf(-2.0f * x)), -1.0f);
}

__global__ __launch_bounds__(256, 2)
void fused_gnn_kernel(const float* __restrict__ node_feat,  // N*21
                      const float* __restrict__ edge_feat,  // N*2
                      const float* __restrict__ W_ih_n,     // 512*21
                      const float* __restrict__ b_ih_n,     // 512
                      const float* __restrict__ b_hh_n,     // 512
                      const float* __restrict__ W_ih_e,     // 512*2
                      const float* __restrict__ b_ih_e,     // 512
                      const float* __restrict__ b_hh_e,     // 512
                      const float* __restrict__ W_nmpn,     // 21*256
                      const float* __restrict__ b_nmpn,     // 21
                      const float* __restrict__ W_fc,       // 4*128
                      const float* __restrict__ b_fc,       // 4
                      float* __restrict__ out,              // N*4
                      int N)
{
    __shared__ float lds[HID * WSTRIDE];   // 63488 B

    const int tid = threadIdx.x;
    const int n = blockIdx.x * blockDim.x + tid;
    const int nidx = (n < N) ? n : (N - 1);

    // ---------------- stage weights into LDS (once per block) ----------------
    if (tid < HID) {
        const int d = tid;
        float* row = &lds[d * WSTRIDE];
#pragma unroll
        for (int k = 0; k < NIN; ++k) {
            row[3 * k + 0] = W_ih_n[(0 * HID + d) * NIN + k];
            row[3 * k + 1] = W_ih_n[(2 * HID + d) * NIN + k];
            row[3 * k + 2] = W_ih_n[(3 * HID + d) * NIN + k];
        }
        row[63] = b_ih_n[0 * HID + d] + b_hh_n[0 * HID + d];
        row[64] = b_ih_n[2 * HID + d] + b_hh_n[2 * HID + d];
        row[65] = b_ih_n[3 * HID + d] + b_hh_n[3 * HID + d];
    } else {
        const int d = tid - HID;
        float* row = &lds[d * WSTRIDE];
        row[66] = W_ih_e[(0 * HID + d) * EIN + 0];
        row[67] = W_ih_e[(0 * HID + d) * EIN + 1];
        row[68] = W_ih_e[(2 * HID + d) * EIN + 0];
        row[69] = W_ih_e[(2 * HID + d) * EIN + 1];
        row[70] = W_ih_e[(3 * HID + d) * EIN + 0];
        row[71] = W_ih_e[(3 * HID + d) * EIN + 1];
        row[72] = b_ih_e[0 * HID + d] + b_hh_e[0 * HID + d];
        row[73] = b_ih_e[2 * HID + d] + b_hh_e[2 * HID + d];
        row[74] = b_ih_e[3 * HID + d] + b_hh_e[3 * HID + d];
#pragma unroll
        for (int k = 0; k < NIN; ++k) {
            row[75 + k] = W_nmpn[k * 2 * HID + d];
            row[96 + k] = W_nmpn[k * 2 * HID + HID + d];
        }
#pragma unroll
        for (int c = 0; c < NCLS; ++c) {
            row[117 + c] = W_fc[c * HID + d];
        }
    }
    __syncthreads();

    // ---------------- per-node inputs ----------------
    float xn[NIN];
#pragma unroll
    for (int k = 0; k < NIN; ++k) xn[k] = node_feat[nidx * NIN + k];
    const float xe0 = edge_feat[nidx * EIN + 0];
    const float xe1 = edge_feat[nidx * EIN + 1];

    float acc[NIN];
#pragma unroll
    for (int k = 0; k < NIN; ++k) acc[k] = b_nmpn[k];
    float lg[NCLS];
#pragma unroll
    for (int k = 0; k < NCLS; ++k) lg[k] = b_fc[k];

    // ================= iteration 1 =================
#pragma unroll 2
    for (int d = 0; d < HID; ++d) {
        const float* row = &lds[d * WSTRIDE];

        float gi = row[63], gg = row[64], go = row[65];
#pragma unroll
        for (int k = 0; k < NIN; ++k) {
            gi = fmaf(xn[k], row[3 * k + 0], gi);
            gg = fmaf(xn[k], row[3 * k + 1], gg);
            go = fmaf(xn[k], row[3 * k + 2], go);
        }
        const float cn = sigmoid_(gi) * tanh_(gg);
        const float hn = sigmoid_(go) * tanh_(cn);

        const float ei = fmaf(xe0, row[66], fmaf(xe1, row[67], row[72]));
        const float eg = fmaf(xe0, row[68], fmaf(xe1, row[69], row[73]));
        const float eo = fmaf(xe0, row[70], fmaf(xe1, row[71], row[74]));
        const float ce = sigmoid_(ei) * tanh_(eg);
        const float he = sigmoid_(eo) * tanh_(ce);

#pragma unroll
        for (int k = 0; k < NIN; ++k) {
            acc[k] = fmaf(he, row[75 + k], fmaf(hn, row[96 + k], acc[k]));
        }
    }

    // xn1 = sigmoid(acc)
#pragma unroll
    for (int k = 0; k < NIN; ++k) xn[k] = sigmoid_(acc[k]);

    // ================= iteration 2 (only h_n matters) =================
#pragma unroll 2
    for (int d = 0; d < HID; ++d) {
        const float* row = &lds[d * WSTRIDE];

        float gi = row[63], gg = row[64], go = row[65];
#pragma unroll
        for (int k = 0; k < NIN; ++k) {
            gi = fmaf(xn[k], row[3 * k + 0], gi);
            gg = fmaf(xn[k], row[3 * k + 1], gg);
            go = fmaf(xn[k], row[3 * k + 2], go);
        }
        const float cn = sigmoid_(gi) * tanh_(gg);
        const float hn = sigmoid_(go) * tanh_(cn);

        lg[0] = fmaf(hn, row[117], lg[0]);
        lg[1] = fmaf(hn, row[118], lg[1]);
        lg[2] = fmaf(hn, row[119], lg[2]);
        lg[3] = fmaf(hn, row[120], lg[3]);
    }

    // ================= log_softmax over 4 classes + store =================
    const float m = fmaxf(fmaxf(lg[0], lg[1]), fmaxf(lg[2], lg[3]));
    float s = 0.0f;
#pragma unroll
    for (int k = 0; k < NCLS; ++k) s += __expf(lg[k] - m);
    const float lse = __logf(s) + m;

    if (n < N) {
        float4 o4;
        o4.x = lg[0] - lse;
        o4.y = lg[1] - lse;
        o4.z = lg[2] - lse;
        o4.w = lg[3] - lse;
        *reinterpret_cast<float4*>(&out[n * NCLS]) = o4;
    }
}

extern "C" void kernel_launch(void* const* d_in, const int* in_sizes, int n_in,
                              void* d_out, int out_size, void* d_ws, size_t ws_size,
                              hipStream_t stream)
{
    // setup_inputs order:
    // 0 node_feat, 1 edge_feat, 2 src, 3 dst, 4 W_ih_n, 5 W_hh_n, 6 b_ih_n,
    // 7 b_hh_n, 8 W_ih_e, 9 W_hh_e, 10 b_ih_e, 11 b_hh_e, 12 W_nmpn,
    // 13 b_nmpn, 14 W_empn, 15 b_empn, 16 W_fc, 17 b_fc
    const float* node_feat = (const float*)d_in[0];
    const float* edge_feat = (const float*)d_in[1];
    const float* W_ih_n    = (const float*)d_in[4];
    const float* b_ih_n    = (const float*)d_in[6];
    const float* b_hh_n    = (const float*)d_in[7];
    const float* W_ih_e    = (const float*)d_in[8];
    const float* b_ih_e    = (const float*)d_in[10];
    const float* b_hh_e    = (const float*)d_in[11];
    const float* W_nmpn    = (const float*)d_in[12];
    const float* b_nmpn    = (const float*)d_in[13];
    const float* W_fc      = (const float*)d_in[16];
    const float* b_fc      = (const float*)d_in[17];
    float* out = (float*)d_out;

    const int N = in_sizes[0] / NIN;

    const int block = 256;
    const int grid = (N + block - 1) / block;
    fused_gnn_kernel<<<grid, block, 0, stream>>>(
        node_feat, edge_feat,
        W_ih_n, b_ih_n, b_hh_n,
        W_ih_e, b_ih_e, b_hh_e,
        W_nmpn, b_nmpn, W_fc, b_fc,
        out, N);
}

// Round 4
// 235.352 us; speedup vs baseline: 1.5960x; 1.1540x over previous
//
#include <hip/hip_runtime.h>

#define HID 128
#define NIN 21
#define EIN 2
#define NCLS 4

// LDS row layout (per hidden-dim d), stride 124 floats (496B = 31*16B, 16B-aligned):
//  [0..62]   node-gate weights interleaved as triples: (wi_k, wg_k, wo_k), k=0..20
//            wi,wo pre-scaled by L=log2(e); wg pre-scaled by 2L
//  [63..65]  combined node biases (same scaling): bi, bg, bo
//  [66..71]  edge weights (scaled): ewi0,ewi1, ewg0,ewg1, ewo0,ewo1
//  [72..74]  combined edge biases (scaled): ebi, ebg, ebo
//  [75..95]  L * W_nmpn[k][d]      (he coefficients), k=0..20
//  [96..116] L * W_nmpn[k][128+d]  (hn coefficients), k=0..20
//  [117..120] W_fc[c][d], c=0..3   (unscaled)
#define WSTRIDE 124

#define L2E   1.4426950408889634f   // log2(e)
#define L2E2  2.8853900817779268f   // 2*log2(e)

__device__ __forceinline__ float rcp_(float x) {
    return __builtin_amdgcn_rcpf(x);
}
__device__ __forceinline__ float exp2_(float x) {
    return __builtin_amdgcn_exp2f(x);
}
// input pre-scaled by L2E:  sigmoid(g) = 1/(1+2^(-g'))
__device__ __forceinline__ float sigmoid_pre(float gp) {
    return rcp_(1.0f + exp2_(-gp));
}
// input pre-scaled by 2*L2E: tanh(g) = 2/(1+2^(-g'')) - 1
__device__ __forceinline__ float tanh_pre(float gp) {
    return fmaf(2.0f, rcp_(1.0f + exp2_(-gp)), -1.0f);
}
// unscaled input
__device__ __forceinline__ float tanh_(float x) {
    return fmaf(2.0f, rcp_(1.0f + exp2_(-L2E2 * x)), -1.0f);
}

__global__ __launch_bounds__(512, 4)
void fused_gnn_kernel(const float* __restrict__ node_feat,  // N*21
                      const float* __restrict__ edge_feat,  // N*2
                      const float* __restrict__ W_ih_n,     // 512*21
                      const float* __restrict__ b_ih_n,     // 512
                      const float* __restrict__ b_hh_n,     // 512
                      const float* __restrict__ W_ih_e,     // 512*2
                      const float* __restrict__ b_ih_e,     // 512
                      const float* __restrict__ b_hh_e,     // 512
                      const float* __restrict__ W_nmpn,     // 21*256
                      const float* __restrict__ b_nmpn,     // 21
                      const float* __restrict__ W_fc,       // 4*128
                      const float* __restrict__ b_fc,       // 4
                      float* __restrict__ out,              // N*4
                      int N)
{
    __shared__ float lds[HID * WSTRIDE];   // 63488 B

    const int tid = threadIdx.x;
    const int n = blockIdx.x * blockDim.x + tid;
    const int nidx = (n < N) ? n : (N - 1);

    // ---------------- stage weights into LDS (once per block) ----------------
    if (tid < HID) {
        const int d = tid;
        float* row = &lds[d * WSTRIDE];
#pragma unroll
        for (int k = 0; k < NIN; ++k) {
            row[3 * k + 0] = L2E  * W_ih_n[(0 * HID + d) * NIN + k];
            row[3 * k + 1] = L2E2 * W_ih_n[(2 * HID + d) * NIN + k];
            row[3 * k + 2] = L2E  * W_ih_n[(3 * HID + d) * NIN + k];
        }
        row[63] = L2E  * (b_ih_n[0 * HID + d] + b_hh_n[0 * HID + d]);
        row[64] = L2E2 * (b_ih_n[2 * HID + d] + b_hh_n[2 * HID + d]);
        row[65] = L2E  * (b_ih_n[3 * HID + d] + b_hh_n[3 * HID + d]);
    } else if (tid < 2 * HID) {
        const int d = tid - HID;
        float* row = &lds[d * WSTRIDE];
        row[66] = L2E  * W_ih_e[(0 * HID + d) * EIN + 0];
        row[67] = L2E  * W_ih_e[(0 * HID + d) * EIN + 1];
        row[68] = L2E2 * W_ih_e[(2 * HID + d) * EIN + 0];
        row[69] = L2E2 * W_ih_e[(2 * HID + d) * EIN + 1];
        row[70] = L2E  * W_ih_e[(3 * HID + d) * EIN + 0];
        row[71] = L2E  * W_ih_e[(3 * HID + d) * EIN + 1];
        row[72] = L2E  * (b_ih_e[0 * HID + d] + b_hh_e[0 * HID + d]);
        row[73] = L2E2 * (b_ih_e[2 * HID + d] + b_hh_e[2 * HID + d]);
        row[74] = L2E  * (b_ih_e[3 * HID + d] + b_hh_e[3 * HID + d]);
#pragma unroll
        for (int k = 0; k < NIN; ++k) {
            row[75 + k] = L2E * W_nmpn[k * 2 * HID + d];
            row[96 + k] = L2E * W_nmpn[k * 2 * HID + HID + d];
        }
#pragma unroll
        for (int c = 0; c < NCLS; ++c) {
            row[117 + c] = W_fc[c * HID + d];
        }
    }
    __syncthreads();

    // ---------------- per-node inputs ----------------
    float xn[NIN];
#pragma unroll
    for (int k = 0; k < NIN; ++k) xn[k] = node_feat[nidx * NIN + k];
    const float xe0 = edge_feat[nidx * EIN + 0];
    const float xe1 = edge_feat[nidx * EIN + 1];

    float acc[NIN];   // accumulates L2E * (xn1 pre-activation)
#pragma unroll
    for (int k = 0; k < NIN; ++k) acc[k] = L2E * b_nmpn[k];
    float lg[NCLS];
#pragma unroll
    for (int k = 0; k < NCLS; ++k) lg[k] = b_fc[k];

    // ================= iteration 1 =================
#pragma unroll 2
    for (int d = 0; d < HID; ++d) {
        const float* row = &lds[d * WSTRIDE];

        float gi = row[63], gg = row[64], go = row[65];
#pragma unroll
        for (int k = 0; k < NIN; ++k) {
            gi = fmaf(xn[k], row[3 * k + 0], gi);
            gg = fmaf(xn[k], row[3 * k + 1], gg);
            go = fmaf(xn[k], row[3 * k + 2], go);
        }
        const float cn = sigmoid_pre(gi) * tanh_pre(gg);
        const float hn = sigmoid_pre(go) * tanh_(cn);

        const float ei = fmaf(xe0, row[66], fmaf(xe1, row[67], row[72]));
        const float eg = fmaf(xe0, row[68], fmaf(xe1, row[69], row[73]));
        const float eo = fmaf(xe0, row[70], fmaf(xe1, row[71], row[74]));
        const float ce = sigmoid_pre(ei) * tanh_pre(eg);
        const float he = sigmoid_pre(eo) * tanh_(ce);

#pragma unroll
        for (int k = 0; k < NIN; ++k) {
            acc[k] = fmaf(he, row[75 + k], fmaf(hn, row[96 + k], acc[k]));
        }
    }

    // xn1 = sigmoid(pre)  — acc already carries the L2E scale
#pragma unroll
    for (int k = 0; k < NIN; ++k) xn[k] = sigmoid_pre(acc[k]);

    // ================= iteration 2 (only h_n matters) =================
#pragma unroll 2
    for (int d = 0; d < HID; ++d) {
        const float* row = &lds[d * WSTRIDE];

        float gi = row[63], gg = row[64], go = row[65];
#pragma unroll
        for (int k = 0; k < NIN; ++k) {
            gi = fmaf(xn[k], row[3 * k + 0], gi);
            gg = fmaf(xn[k], row[3 * k + 1], gg);
            go = fmaf(xn[k], row[3 * k + 2], go);
        }
        const float cn = sigmoid_pre(gi) * tanh_pre(gg);
        const float hn = sigmoid_pre(go) * tanh_(cn);

        lg[0] = fmaf(hn, row[117], lg[0]);
        lg[1] = fmaf(hn, row[118], lg[1]);
        lg[2] = fmaf(hn, row[119], lg[2]);
        lg[3] = fmaf(hn, row[120], lg[3]);
    }

    // ================= log_softmax over 4 classes + store =================
    const float m = fmaxf(fmaxf(lg[0], lg[1]), fmaxf(lg[2], lg[3]));
    float s = 0.0f;
#pragma unroll
    for (int k = 0; k < NCLS; ++k) s += exp2_(L2E * (lg[k] - m));
    const float lse = __logf(s) + m;

    if (n < N) {
        float4 o4;
        o4.x = lg[0] - lse;
        o4.y = lg[1] - lse;
        o4.z = lg[2] - lse;
        o4.w = lg[3] - lse;
        *reinterpret_cast<float4*>(&out[n * NCLS]) = o4;
    }
}

extern "C" void kernel_launch(void* const* d_in, const int* in_sizes, int n_in,
                              void* d_out, int out_size, void* d_ws, size_t ws_size,
                              hipStream_t stream)
{
    // setup_inputs order:
    // 0 node_feat, 1 edge_feat, 2 src, 3 dst, 4 W_ih_n, 5 W_hh_n, 6 b_ih_n,
    // 7 b_hh_n, 8 W_ih_e, 9 W_hh_e, 10 b_ih_e, 11 b_hh_e, 12 W_nmpn,
    // 13 b_nmpn, 14 W_empn, 15 b_empn, 16 W_fc, 17 b_fc
    const float* node_feat = (const float*)d_in[0];
    const float* edge_feat = (const float*)d_in[1];
    const float* W_ih_n    = (const float*)d_in[4];
    const float* b_ih_n    = (const float*)d_in[6];
    const float* b_hh_n    = (const float*)d_in[7];
    const float* W_ih_e    = (const float*)d_in[8];
    const float* b_ih_e    = (const float*)d_in[10];
    const float* b_hh_e    = (const float*)d_in[11];
    const float* W_nmpn    = (const float*)d_in[12];
    const float* b_nmpn    = (const float*)d_in[13];
    const float* W_fc      = (const float*)d_in[16];
    const float* b_fc      = (const float*)d_in[17];
    float* out = (float*)d_out;

    const int N = in_sizes[0] / NIN;

    const int block = 512;   // 8 waves/block; 2 blocks/CU (127KB LDS) -> 16 waves/CU
    const int grid = (N + block - 1) / block;
    fused_gnn_kernel<<<grid, block, 0, stream>>>(
        node_feat, edge_feat,
        W_ih_n, b_ih_n, b_hh_n,
        W_ih_e, b_ih_e, b_hh_e,
        W_nmpn, b_nmpn, W_fc, b_fc,
        out, N);
}